// Round 11
// baseline (365.362 us; speedup 1.0000x reference)
//
#include <hip/hip_runtime.h>
#include <hip/hip_bf16.h>
#include <math.h>

#define D_MODEL 768
#define NH 16
#define DH 48
#define NP 4
#define LQ 4096
#define BB 2
#define MTOT (BB * LQ)  // 8192

typedef __attribute__((ext_vector_type(8))) _Float16 half8_t;
typedef __attribute__((ext_vector_type(4))) float floatx4;

__device__ __forceinline__ void load_lds16(const void* g, void* l) {
    __builtin_amdgcn_global_load_lds((const __attribute__((address_space(1))) void*)g,
                                     (__attribute__((address_space(3))) void*)l, 16, 0, 0);
}

// ---------------------------------------------------------------------------
// fp16 MFMA GEMM tile body, 2-phase double-buffered (proven 32 KB / high-occ
// structure). AFP32: A is fp32, reg-staged (load->cvt->ds_write); W always
// fp16 via global_load_lds. 128x128 tile, BK=32, 4 waves, 4x4 16x16x32 MFMA.
// MODE 1: fp32 C = gamma*(attn16 + acc + b) (final)
// MODE 2: fp16 C = acc + bias               (everything else)
// ---------------------------------------------------------------------------
template <int MODE, bool AFP32>
__device__ __forceinline__ void gemm_body(
    const void* __restrict__ Av, const _Float16* __restrict__ Wt,
    const float* __restrict__ bias, void* __restrict__ Cv, int ldc,
    int tm, int tn,
    const _Float16* __restrict__ attn, const float* __restrict__ gamma)
{
    constexpr int K = 768;
    constexpr int NT = K / 32;  // 24 K-steps
    __shared__ _Float16 As[2][128 * 32];   // 2 x 8 KB
    __shared__ _Float16 Bs[2][128 * 32];   // 2 x 8 KB

    const int bm = tm * 128, bn = tn * 128;
    const int t = threadIdx.x;
    const int lane = t & 63;
    const int w = t >> 6;
    const int wm = (w >> 1) * 64, wn = (w & 1) * 64;

    floatx4 acc[4][4] = {};

    const int r0 = t >> 2;           // 0..63
    const int c8 = (t & 3) * 8;      // 0/8/16/24
    const size_t brow0 = (size_t)(bn + r0) * K + c8;
    const size_t brow1 = (size_t)(bn + 64 + r0) * K + c8;

    const int lrow = lane & 15;
    const int lk = (lane >> 4) * 8;

    const _Float16* A16 = (const _Float16*)Av;
    const float* A32 = (const float*)Av;
    const size_t arow0 = (size_t)(bm + r0) * K + c8;
    const size_t arow1 = (size_t)(bm + 64 + r0) * K + c8;

    float4 ar[4];  // AFP32 staging regs (2 rows x 8 floats)

    auto STAGE_B = [&](int kt, int buf) {
        load_lds16(Wt + brow0 + kt, &Bs[buf][w * 512]);
        load_lds16(Wt + brow1 + kt, &Bs[buf][2048 + w * 512]);
    };
    auto STAGE_A16 = [&](int kt, int buf) {
        load_lds16(A16 + arow0 + kt, &As[buf][w * 512]);
        load_lds16(A16 + arow1 + kt, &As[buf][2048 + w * 512]);
    };
    auto LOAD_A32 = [&](int kt) {
        const float* p0 = A32 + arow0 + kt;
        const float* p1 = A32 + arow1 + kt;
        ar[0] = *(const float4*)p0; ar[1] = *(const float4*)(p0 + 4);
        ar[2] = *(const float4*)p1; ar[3] = *(const float4*)(p1 + 4);
    };
    auto WRITE_A32 = [&](int buf) {
        _Float16 h0[8] = {(_Float16)ar[0].x, (_Float16)ar[0].y, (_Float16)ar[0].z, (_Float16)ar[0].w,
                          (_Float16)ar[1].x, (_Float16)ar[1].y, (_Float16)ar[1].z, (_Float16)ar[1].w};
        _Float16 h1[8] = {(_Float16)ar[2].x, (_Float16)ar[2].y, (_Float16)ar[2].z, (_Float16)ar[2].w,
                          (_Float16)ar[3].x, (_Float16)ar[3].y, (_Float16)ar[3].z, (_Float16)ar[3].w};
        *(half8_t*)&As[buf][r0 * 32 + c8] = *(half8_t*)h0;
        *(half8_t*)&As[buf][2048 + r0 * 32 + c8] = *(half8_t*)h1;
    };

    // prologue: stage K-step 0 into buffer 0
    STAGE_B(0, 0);
    if constexpr (AFP32) {
        LOAD_A32(0);
        asm volatile("s_waitcnt vmcnt(0)" ::: "memory");
        WRITE_A32(0);
    } else {
        STAGE_A16(0, 0);
    }
    __syncthreads();

    for (int ti = 0; ti < NT; ++ti) {
        const int cur = ti & 1;
        const int nxt = cur ^ 1;
        if (ti + 1 < NT) {
            const int kn = (ti + 1) * 32;
            STAGE_B(kn, nxt);
            if constexpr (AFP32) LOAD_A32(kn);
            else                 STAGE_A16(kn, nxt);
        }

        const _Float16* Ac = As[cur];
        const _Float16* Bc = Bs[cur];
        half8_t af[4], bf[4];
#pragma unroll
        for (int i = 0; i < 4; ++i) {
            af[i] = *(const half8_t*)&Ac[(wm + i * 16 + lrow) * 32 + lk];
            bf[i] = *(const half8_t*)&Bc[(wn + i * 16 + lrow) * 32 + lk];
        }
#pragma unroll
        for (int i = 0; i < 4; ++i)
#pragma unroll
            for (int j = 0; j < 4; ++j)
                acc[i][j] = __builtin_amdgcn_mfma_f32_16x16x32_f16(af[i], bf[j], acc[i][j], 0, 0, 0);

        if (ti + 1 < NT) {
            if constexpr (AFP32) {
                asm volatile("s_waitcnt vmcnt(0)" ::: "memory");  // A regs (and B lds) ready
                WRITE_A32(nxt);
            }
            __syncthreads();
        }
    }

    // epilogue: C/D layout col=lane&15, row=(lane>>4)*4+reg
    const int rquad = (lane >> 4) * 4;
#pragma unroll
    for (int i = 0; i < 4; ++i) {
#pragma unroll
        for (int j = 0; j < 4; ++j) {
            const int col = bn + wn + j * 16 + lrow;
            const float bcol = bias[col];
#pragma unroll
            for (int r = 0; r < 4; ++r) {
                const size_t row = (size_t)(bm + wm + i * 16 + rquad + r);
                float v = acc[i][j][r] + bcol;
                if constexpr (MODE == 1) {
                    v = ((float)attn[row * (size_t)ldc + col] + v) * gamma[col];
                    ((float*)Cv)[row * (size_t)ldc + col] = v;
                } else {
                    ((_Float16*)Cv)[row * (size_t)ldc + col] = (_Float16)v;
                }
            }
        }
    }
}

// ---------------------------------------------------------------------------
// Weight transpose block: W(768x768 fp32) tile (32x32) -> Wt fp16 transposed.
// ---------------------------------------------------------------------------
__device__ __forceinline__ void wt_transpose_block(
    const float* __restrict__ W, _Float16* __restrict__ Wt, int gx, int t,
    float (*tile)[33])
{
    const int tk0 = (gx / 24) * 32;
    const int tn0 = (gx % 24) * 32;
#pragma unroll
    for (int r = 0; r < 4; ++r) {
        const int row = r * 8 + (t >> 5);
        const int col = t & 31;
        tile[row][col] = W[(size_t)(tk0 + row) * 768 + tn0 + col];
    }
    __syncthreads();
    const int n = t >> 3;
    const int kq = (t & 7) * 4;
    _Float16* dst = Wt + (size_t)(tn0 + n) * 768 + tk0 + kq;
#pragma unroll
    for (int u = 0; u < 4; ++u) dst[u] = (_Float16)tile[kq + u][n];
}

// Small first dispatch: convert only W_qn, W_fn (needed by G1).
__global__ __launch_bounds__(256) void convert_w2(
    const float* __restrict__ w0, const float* __restrict__ w1,
    _Float16* __restrict__ Wall)
{
    __shared__ float tile[32][33];
    const int wi = blockIdx.x / 576;
    const int gx = blockIdx.x % 576;
    wt_transpose_block(wi ? w1 : w0, Wall + (size_t)wi * 768 * 768, gx, threadIdx.x, tile);
}

// ---------------------------------------------------------------------------
// G1 mega-dispatch: [0,384) qn GEMM (A=query fp32); [384,768) fn GEMM
// (A=feat fp32); [768,3072) transpose cWv/cWo/sWv/sWo; [3072,3456) offa conv.
// Conversion blocks overlap the GEMM blocks on idle CUs.
// ---------------------------------------------------------------------------
__global__ __launch_bounds__(256) void g1_mega(
    const float* __restrict__ query, const _Float16* __restrict__ Wq,
    const float* __restrict__ bq_, _Float16* __restrict__ Cq,
    const float* __restrict__ feat, const _Float16* __restrict__ Wf,
    const float* __restrict__ bf_, _Float16* __restrict__ Cf,
    const float* __restrict__ w2, const float* __restrict__ w3,
    const float* __restrict__ w4, const float* __restrict__ w5,
    _Float16* __restrict__ Wall,
    const float* __restrict__ Woff_c, const float* __restrict__ Wa_c,
    const float* __restrict__ boff_c, const float* __restrict__ ba_c,
    const float* __restrict__ Woff_s, const float* __restrict__ Wa_s,
    const float* __restrict__ boff_s, const float* __restrict__ ba_s,
    _Float16* __restrict__ Wc, _Float16* __restrict__ Ws,
    float* __restrict__ bias_c, float* __restrict__ bias_s)
{
    __shared__ float tile[32][33];
    const int bid = blockIdx.x;
    const int t = threadIdx.x;

    if (bid < 768) {
        int b = (bid < 384) ? bid : bid - 384;
        const int swz = (b & 7) * 48 + (b >> 3);
        if (bid < 384)
            gemm_body<2, true>(query, Wq, bq_, Cq, 768, swz & 63, swz >> 6, nullptr, nullptr);
        else
            gemm_body<2, true>(feat, Wf, bf_, Cf, 768, swz & 63, swz >> 6, nullptr, nullptr);
    } else if (bid < 3072) {
        const int g = bid - 768;
        const int wi = g / 576;   // 0..3 -> slots 2..5
        const int gx = g - wi * 576;
        const float* W = (wi == 0) ? w2 : (wi == 1) ? w3 : (wi == 2) ? w4 : w5;
        wt_transpose_block(W, Wall + (size_t)(wi + 2) * 768 * 768, gx, t, tile);
    } else {
        const int i = (bid - 3072) * 256 + t;  // 2*256*192 = 98304
        const int pair = i / (256 * 192);
        const int r = i - pair * (256 * 192);
        const int n = r / 192;
        const int k0 = (r - n * 192) * 4;
        const float* Woff = pair ? Woff_s : Woff_c;
        const float* Wa = pair ? Wa_s : Wa_c;
        _Float16* dst = pair ? Ws : Wc;
        _Float16* row = dst + (size_t)n * 768;
#pragma unroll
        for (int u = 0; u < 4; ++u) {
            const int k = k0 + u;
            float v = (n < 128) ? Woff[(size_t)k * 128 + n]
                    : (n < 192) ? Wa[(size_t)k * 64 + (n - 128)] : 0.f;
            row[k] = (_Float16)v;
        }
        if (k0 == 0) {
            const float* boff = pair ? boff_s : boff_c;
            const float* ba = pair ? ba_s : ba_c;
            float* bias = pair ? bias_s : bias_c;
            bias[n] = (n < 128) ? boff[n] : (n < 192) ? ba[n - 128] : 0.f;
        }
    }
}

// Single GEMM: N=768 (6 col tiles), 384 blocks, XCD-swizzled. fp16 A.
template <int MODE>
__global__ __launch_bounds__(256) void gemm_mfma(
    const _Float16* __restrict__ A, const _Float16* __restrict__ Wt,
    const float* __restrict__ bias, void* __restrict__ C,
    const _Float16* __restrict__ attn, const float* __restrict__ gamma)
{
    const int bid = blockIdx.x;
    const int swz = (bid & 7) * 48 + (bid >> 3);
    gemm_body<MODE, false>(A, Wt, bias, C, 768, swz & 63, swz >> 6, attn, gamma);
}

// Dual GEMM (fp16 A both jobs): counts divisible by 8.
__global__ __launch_bounds__(256) void dual_gemm(
    const _Float16* __restrict__ A0, const _Float16* __restrict__ W0,
    const float* __restrict__ b0, void* __restrict__ C0, int ldc0, int cnt0,
    const _Float16* __restrict__ A1, const _Float16* __restrict__ W1,
    const float* __restrict__ b1, void* __restrict__ C1, int ldc1, int cnt1)
{
    int bid = blockIdx.x;
    if (bid < cnt0) {
        const int q = cnt0 >> 3;
        const int swz = (bid & 7) * q + (bid >> 3);
        gemm_body<2, false>(A0, W0, b0, C0, ldc0, swz & 63, swz >> 6, nullptr, nullptr);
    } else {
        bid -= cnt0;
        const int q = cnt1 >> 3;
        const int swz = (bid & 7) * q + (bid >> 3);
        gemm_body<2, false>(A1, W1, b1, C1, ldc1, swz & 63, swz >> 6, nullptr, nullptr);
    }
}

// ---------------------------------------------------------------------------
// LayerNorm, wave-per-row, fp16 in -> fp16 out. In-place safe.
// ---------------------------------------------------------------------------
__device__ __forceinline__ void ln_wave_body(
    const _Float16* __restrict__ X, _Float16* __restrict__ A,
    const float* __restrict__ g, const float* __restrict__ beta, int row)
{
    const int lane = threadIdx.x & 63;
    const _Float16* x = X + (size_t)row * D_MODEL;
    float v[12];
    float s = 0.f, s2 = 0.f;
#pragma unroll
    for (int j = 0; j < 12; ++j) {
        v[j] = (float)x[lane + 64 * j];
        s += v[j];
        s2 += v[j] * v[j];
    }
#pragma unroll
    for (int m = 1; m < 64; m <<= 1) {
        s += __shfl_xor(s, m);
        s2 += __shfl_xor(s2, m);
    }
    const float mean = s * (1.f / 768.f);
    const float var = s2 * (1.f / 768.f) - mean * mean;
    const float rstd = rsqrtf(var + 1e-6f);
    _Float16* arow = A + (size_t)row * D_MODEL;
#pragma unroll
    for (int j = 0; j < 12; ++j) {
        const int cc = lane + 64 * j;
        arow[cc] = (_Float16)((v[j] - mean) * rstd * g[cc] + beta[cc]);
    }
}

__global__ __launch_bounds__(256) void ln2_wave(
    const _Float16* __restrict__ X0, _Float16* __restrict__ A0,
    const float* __restrict__ g0, const float* __restrict__ b0,
    const _Float16* __restrict__ X1, _Float16* __restrict__ A1,
    const float* __restrict__ g1, const float* __restrict__ b1)
{
    const int r = blockIdx.x * 4 + (threadIdx.x >> 6);
    if (r < MTOT) ln_wave_body(X0, A0, g0, b0, r);
    else          ln_wave_body(X1, A1, g1, b1, r - MTOT);
}

__global__ __launch_bounds__(256) void ln_wave(
    const _Float16* __restrict__ X, _Float16* __restrict__ A,
    const float* __restrict__ g, const float* __restrict__ beta)
{
    const int r = blockIdx.x * 4 + (threadIdx.x >> 6);
    ln_wave_body(X, A, g, beta, r);
}

// ---------------------------------------------------------------------------
// Fused softmax/loc + bilinear sampling. 192-thread blocks, each covers 2 bq.
// offc is fp16 (M x 256): off at 0, aw at 128. XCD-chunk swizzle.
// ---------------------------------------------------------------------------
__global__ __launch_bounds__(192) void sample_fused(
    const _Float16* __restrict__ value, const _Float16* __restrict__ offc,
    _Float16* __restrict__ A)
{
    __shared__ float loc_s[32][8];
    __shared__ float aw_s[32][4];

    const int bid = blockIdx.x;                    // 4096 = 8 * 512
    const int swz = (bid & 7) * 512 + (bid >> 3);  // XCD-chunk swizzle
    const int bq_base = swz * 2;
    const int t = threadIdx.x;

    if (t < 32) {
        const int bq = bq_base + (t >> 4);
        const int h = t & 15;
        const int q = bq & (LQ - 1);
        const _Float16* orow = offc + (size_t)bq * 256 + h * 8;
        const _Float16* arow = offc + (size_t)bq * 256 + 128 + h * 4;
        float a0 = (float)arow[0], a1 = (float)arow[1], a2 = (float)arow[2], a3 = (float)arow[3];
        float mx = fmaxf(fmaxf(a0, a1), fmaxf(a2, a3));
        float e0 = expf(a0 - mx), e1 = expf(a1 - mx), e2 = expf(a2 - mx), e3 = expf(a3 - mx);
        float r = 1.f / (e0 + e1 + e2 + e3);
        const float refx = ((q & 63) + 0.5f) * (1.f / 64.f);
        const float refy = ((q >> 6) + 0.5f) * (1.f / 64.f);
#pragma unroll
        for (int p = 0; p < 4; ++p) {
            loc_s[t][p * 2 + 0] = refx + (float)orow[p * 2 + 0] * (1.f / 64.f);
            loc_s[t][p * 2 + 1] = refy + (float)orow[p * 2 + 1] * (1.f / 64.f);
        }
        aw_s[t][0] = e0 * r; aw_s[t][1] = e1 * r;
        aw_s[t][2] = e2 * r; aw_s[t][3] = e3 * r;
    }
    __syncthreads();

    const int lbqh = t / 6;
    const int c = t - lbqh * 6;
    const int d0 = c * 8;
    const int bq = bq_base + (lbqh >> 4);
    const int h = lbqh & 15;
    const int b = bq >> 12;

    const _Float16* vbase = value + (size_t)b * LQ * D_MODEL + h * DH + d0;

    float acc[8] = {};
#pragma unroll
    for (int p = 0; p < 4; ++p) {
        const float x = loc_s[lbqh][p * 2 + 0] * 64.f - 0.5f;
        const float y = loc_s[lbqh][p * 2 + 1] * 64.f - 0.5f;
        const float xf = floorf(x), yf = floorf(y);
        const float wx1 = x - xf, wy1 = y - yf;
        const float wx0 = 1.f - wx1, wy0 = 1.f - wy1;
        const int x0 = (int)xf, y0 = (int)yf;
        const int x1 = x0 + 1, y1 = y0 + 1;
        const float wp = aw_s[lbqh][p];
        const bool vx0 = (x0 >= 0) && (x0 < 64);
        const bool vx1 = (x1 >= 0) && (x1 < 64);
        const bool vy0 = (y0 >= 0) && (y0 < 64);
        const bool vy1 = (y1 >= 0) && (y1 < 64);
        const float cw[4] = {wp * wx0 * wy0, wp * wx1 * wy0, wp * wx0 * wy1, wp * wx1 * wy1};
        const bool cv[4] = {vx0 && vy0, vx1 && vy0, vx0 && vy1, vx1 && vy1};
        const int cxy[4][2] = {{x0, y0}, {x1, y0}, {x0, y1}, {x1, y1}};
#pragma unroll
        for (int k = 0; k < 4; ++k) {
            if (cv[k]) {
                const half8_t g = *(const half8_t*)(vbase + (size_t)(cxy[k][1] * 64 + cxy[k][0]) * D_MODEL);
#pragma unroll
                for (int u = 0; u < 8; ++u) acc[u] += cw[k] * (float)g[u];
            }
        }
    }

    _Float16* arow = A + (size_t)bq * D_MODEL + h * DH + d0;
    _Float16 o[8];
#pragma unroll
    for (int u = 0; u < 8; ++u) o[u] = (_Float16)acc[u];
    *(uint4*)arow = *(uint4*)o;
}

// ---------------------------------------------------------------------------
extern "C" void kernel_launch(void* const* d_in, const int* in_sizes, int n_in,
                              void* d_out, int out_size, void* d_ws, size_t ws_size,
                              hipStream_t stream)
{
    const float* query   = (const float*)d_in[0];
    const float* feat    = (const float*)d_in[1];
    const float* qn_W    = (const float*)d_in[4];
    const float* qn_b    = (const float*)d_in[5];
    const float* qn_g    = (const float*)d_in[6];
    const float* qn_beta = (const float*)d_in[7];
    const float* fn_W    = (const float*)d_in[8];
    const float* fn_b    = (const float*)d_in[9];
    const float* fn_g    = (const float*)d_in[10];
    const float* fn_beta = (const float*)d_in[11];
    const float* nm_g    = (const float*)d_in[12];
    const float* nm_beta = (const float*)d_in[13];
    const float* gamma1  = (const float*)d_in[14];
    const float* c_Wv    = (const float*)d_in[15];
    const float* c_bv    = (const float*)d_in[16];
    const float* c_Woff  = (const float*)d_in[17];
    const float* c_boff  = (const float*)d_in[18];
    const float* c_Wa    = (const float*)d_in[19];
    const float* c_ba    = (const float*)d_in[20];
    const float* c_Wo    = (const float*)d_in[21];
    const float* c_bo    = (const float*)d_in[22];
    const float* s_Wv    = (const float*)d_in[23];
    const float* s_bv    = (const float*)d_in[24];
    const float* s_Woff  = (const float*)d_in[25];
    const float* s_boff  = (const float*)d_in[26];
    const float* s_Wa    = (const float*)d_in[27];
    const float* s_ba    = (const float*)d_in[28];
    const float* s_Wo    = (const float*)d_in[29];
    const float* s_bo    = (const float*)d_in[30];

    const size_t SZ = (size_t)MTOT * D_MODEL;  // 6291456 elements
    _Float16* hA    = (_Float16*)d_ws;         // attn16
    _Float16* hB    = hA + SZ;                 // samp16
    _Float16* hQ    = hB + SZ;                 // qn16 -> attn1n16
    _Float16* hF    = hQ + SZ;                 // fn16
    _Float16* val16 = hF + SZ;                 // value fp16
    _Float16* offc  = val16 + SZ;              // M x 256 fp16
    float* bias_c = (float*)(offc + (size_t)MTOT * 256);
    float* bias_s = bias_c + 256;
    _Float16* W6 = (_Float16*)(bias_s + 256);  // 6 x 768 x 768 fp16
    _Float16* W_qn  = W6 + (size_t)0 * 768 * 768;
    _Float16* W_fn  = W6 + (size_t)1 * 768 * 768;
    _Float16* W_cWv = W6 + (size_t)2 * 768 * 768;
    _Float16* W_cWo = W6 + (size_t)3 * 768 * 768;
    _Float16* W_sWv = W6 + (size_t)4 * 768 * 768;
    _Float16* W_sWo = W6 + (size_t)5 * 768 * 768;
    _Float16* Woffa_c = W6 + (size_t)6 * 768 * 768;  // 256 x 768
    _Float16* Woffa_s = Woffa_c + (size_t)256 * 768;

    float* out = (float*)d_out;
    const dim3 blk(256);

    // 1) convert only the weights G1 needs
    convert_w2<<<1152, blk, 0, stream>>>(qn_W, fn_W, W6);

    // 2) G1 mega: qn/fn GEMM straight from fp32 + all other weight conversions
    g1_mega<<<3456, blk, 0, stream>>>(
        query, W_qn, qn_b, hQ,
        feat, W_fn, fn_b, hF,
        c_Wv, c_Wo, s_Wv, s_Wo, W6,
        c_Woff, c_Wa, c_boff, c_ba, s_Woff, s_Wa, s_boff, s_ba,
        Woffa_c, Woffa_s, bias_c, bias_s);

    // ---- cross attention ----
    ln2_wave<<<2 * MTOT / 4, blk, 0, stream>>>(hQ, hQ, qn_g, qn_beta,
                                               hF, hF, fn_g, fn_beta);
    dual_gemm<<<512, blk, 0, stream>>>(hF, W_cWv, c_bv, val16, 768, 384,
                                       hQ, Woffa_c, bias_c, offc, 256, 128);
    sample_fused<<<4096, dim3(192), 0, stream>>>(val16, offc, hB);
    gemm_mfma<2><<<384, blk, 0, stream>>>(hB, W_cWo, c_bo, hA, nullptr, nullptr);  // attn16

    // ---- self attention ----
    ln_wave<<<MTOT / 4, blk, 0, stream>>>(hA, hQ, nm_g, nm_beta);  // attn1 -> hQ
    dual_gemm<<<512, blk, 0, stream>>>(hQ, W_sWv, s_bv, val16, 768, 384,
                                       hQ, Woffa_s, bias_s, offc, 256, 128);
    sample_fused<<<4096, dim3(192), 0, stream>>>(val16, offc, hB);
    // final: out = gamma1 * (attn16 + samp@s_Wo + s_bo)
    gemm_mfma<1><<<384, blk, 0, stream>>>(hB, W_sWo, s_bo, out, hA, gamma1);
}

// Round 12
// 350.828 us; speedup vs baseline: 1.0414x; 1.0414x over previous
//
#include <hip/hip_runtime.h>
#include <hip/hip_bf16.h>
#include <math.h>

#define D_MODEL 768
#define NH 16
#define DH 48
#define NP 4
#define LQ 4096
#define BB 2
#define MTOT (BB * LQ)  // 8192

typedef __attribute__((ext_vector_type(8))) _Float16 half8_t;
typedef __attribute__((ext_vector_type(4))) float floatx4;

__device__ __forceinline__ void load_lds16(const void* g, void* l) {
    __builtin_amdgcn_global_load_lds((const __attribute__((address_space(1))) void*)g,
                                     (__attribute__((address_space(3))) void*)l, 16, 0, 0);
}

// ---------------------------------------------------------------------------
// fp16 MFMA GEMM tile body, 2-phase double-buffered (proven 32 KB / high-occ
// structure). Shared buffers are PASSED IN so callers can alias them for
// non-GEMM branches without growing the block's LDS footprint.
// A: (M x 768 fp16); Wt: (ldc x 768 fp16, transposed). 128x128 tile, BK=32,
// 4 waves (2x2), 4x4 16x16x32 MFMA per wave.
// MODE 1: fp32 C = gamma*(attn16 + acc + b) (final)
// MODE 2: fp16 C = acc + bias               (everything else)
// ---------------------------------------------------------------------------
template <int MODE>
__device__ __forceinline__ void gemm_body(
    const _Float16* __restrict__ A, const _Float16* __restrict__ Wt,
    const float* __restrict__ bias, void* __restrict__ Cv, int ldc,
    int tm, int tn,
    const _Float16* __restrict__ attn, const float* __restrict__ gamma,
    _Float16* AsB, _Float16* BsB)   // each 2*4096 elements (16 KB)
{
    constexpr int K = 768;
    constexpr int NT = K / 32;  // 24 K-steps

    const int bm = tm * 128, bn = tn * 128;
    const int t = threadIdx.x;
    const int lane = t & 63;
    const int w = t >> 6;
    const int wm = (w >> 1) * 64, wn = (w & 1) * 64;

    floatx4 acc[4][4] = {};

    const int r0 = t >> 2;
    const int c8 = (t & 3) * 8;
    const size_t arow0 = (size_t)(bm + r0) * K + c8;
    const size_t arow1 = (size_t)(bm + 64 + r0) * K + c8;
    const size_t brow0 = (size_t)(bn + r0) * K + c8;
    const size_t brow1 = (size_t)(bn + 64 + r0) * K + c8;

    const int lrow = lane & 15;
    const int lk = (lane >> 4) * 8;

    auto STAGE = [&](int kt, int buf) {
        _Float16* as = AsB + (buf << 12);
        _Float16* bs = BsB + (buf << 12);
        load_lds16(A + arow0 + kt, as + w * 512);
        load_lds16(A + arow1 + kt, as + 2048 + w * 512);
        load_lds16(Wt + brow0 + kt, bs + w * 512);
        load_lds16(Wt + brow1 + kt, bs + 2048 + w * 512);
    };

    STAGE(0, 0);
    __syncthreads();

    for (int ti = 0; ti < NT; ++ti) {
        const int cur = ti & 1;
        if (ti + 1 < NT) STAGE((ti + 1) * 32, cur ^ 1);

        const _Float16* Ac = AsB + (cur << 12);
        const _Float16* Bc = BsB + (cur << 12);
        half8_t af[4], bf[4];
#pragma unroll
        for (int i = 0; i < 4; ++i) {
            af[i] = *(const half8_t*)&Ac[(wm + i * 16 + lrow) * 32 + lk];
            bf[i] = *(const half8_t*)&Bc[(wn + i * 16 + lrow) * 32 + lk];
        }
#pragma unroll
        for (int i = 0; i < 4; ++i)
#pragma unroll
            for (int j = 0; j < 4; ++j)
                acc[i][j] = __builtin_amdgcn_mfma_f32_16x16x32_f16(af[i], bf[j], acc[i][j], 0, 0, 0);

        if (ti + 1 < NT) __syncthreads();
    }

    // epilogue: C/D layout col=lane&15, row=(lane>>4)*4+reg
    const int rquad = (lane >> 4) * 4;
#pragma unroll
    for (int i = 0; i < 4; ++i) {
#pragma unroll
        for (int j = 0; j < 4; ++j) {
            const int col = bn + wn + j * 16 + lrow;
            const float bcol = bias[col];
#pragma unroll
            for (int r = 0; r < 4; ++r) {
                const size_t row = (size_t)(bm + wm + i * 16 + rquad + r);
                float v = acc[i][j][r] + bcol;
                if constexpr (MODE == 1) {
                    v = ((float)attn[row * (size_t)ldc + col] + v) * gamma[col];
                    ((float*)Cv)[row * (size_t)ldc + col] = v;
                } else {
                    ((_Float16*)Cv)[row * (size_t)ldc + col] = (_Float16)v;
                }
            }
        }
    }
}

// ---------------------------------------------------------------------------
// Weight transpose block: W(768x768 fp32) 32x32 tile -> Wt fp16 transposed.
// tile points into aliased LDS (4224 B needed).
// ---------------------------------------------------------------------------
__device__ __forceinline__ void wt_transpose_block(
    const float* __restrict__ W, _Float16* __restrict__ Wt, int gx, int t,
    float (*tile)[33])
{
    const int tk0 = (gx / 24) * 32;
    const int tn0 = (gx % 24) * 32;
#pragma unroll
    for (int r = 0; r < 4; ++r) {
        const int row = r * 8 + (t >> 5);
        const int col = t & 31;
        tile[row][col] = W[(size_t)(tk0 + row) * 768 + tn0 + col];
    }
    __syncthreads();
    const int n = t >> 3;
    const int kq = (t & 7) * 4;
    _Float16* dst = Wt + (size_t)(tn0 + n) * 768 + tk0 + kq;
#pragma unroll
    for (int u = 0; u < 4; ++u) dst[u] = (_Float16)tile[kq + u][n];
}

// ---------------------------------------------------------------------------
// Pre-convert: [0,12288) acts fp32->fp16 (query->hA, feat->hB);
// [12288,13440) transpose W_qn, W_fn (needed by G1).
// ---------------------------------------------------------------------------
__global__ __launch_bounds__(256) void convert_pre(
    const float* __restrict__ query, _Float16* __restrict__ actA,
    const float* __restrict__ feat, _Float16* __restrict__ actB,
    const float* __restrict__ w0, const float* __restrict__ w1,
    _Float16* __restrict__ Wall)
{
    __shared__ float tile[32][33];
    const int bid = blockIdx.x;
    const int t = threadIdx.x;

    if (bid < 12288) {
        const int i = bid * 256 + t;
        const int sel = i / (MTOT * 192);
        const int r = i - sel * (MTOT * 192);
        const float* X = sel ? feat : query;
        _Float16* D = sel ? actB : actA;
        const int c4 = r * 4;
        const float4 v = *(const float4*)(X + (size_t)c4);
        _Float16 o[4] = {(_Float16)v.x, (_Float16)v.y, (_Float16)v.z, (_Float16)v.w};
        *(uint2*)(D + (size_t)c4) = *(uint2*)o;
    } else {
        const int g = bid - 12288;       // 0..1151
        const int wi = g / 576;          // 0 (qn) or 1 (fn)
        const int gx = g - wi * 576;
        wt_transpose_block(wi ? w1 : w0, Wall + (size_t)wi * 768 * 768, gx, t, tile);
    }
}

// ---------------------------------------------------------------------------
// G1 mega: [0,384) qn GEMM; [384,768) fn GEMM (both fp16-A, proven body);
// [768,3072) transpose cWv/cWo/sWv/sWo; [3072,3456) offa weights + bias.
// Non-GEMM branches ALIAS the GEMM's 32 KB shared buffers -> LDS stays 32768.
// ---------------------------------------------------------------------------
__global__ __launch_bounds__(256) void g1_mega(
    const _Float16* __restrict__ actA, const _Float16* __restrict__ Wq,
    const float* __restrict__ bq_, _Float16* __restrict__ Cq,
    const _Float16* __restrict__ actB, const _Float16* __restrict__ Wf,
    const float* __restrict__ bf_, _Float16* __restrict__ Cf,
    const float* __restrict__ w2, const float* __restrict__ w3,
    const float* __restrict__ w4, const float* __restrict__ w5,
    _Float16* __restrict__ Wall,
    const float* __restrict__ Woff_c, const float* __restrict__ Wa_c,
    const float* __restrict__ boff_c, const float* __restrict__ ba_c,
    const float* __restrict__ Woff_s, const float* __restrict__ Wa_s,
    const float* __restrict__ boff_s, const float* __restrict__ ba_s,
    _Float16* __restrict__ Wc, _Float16* __restrict__ Ws,
    float* __restrict__ bias_c, float* __restrict__ bias_s)
{
    __shared__ _Float16 AsS[2 * 4096];   // 16 KB
    __shared__ _Float16 BsS[2 * 4096];   // 16 KB
    const int bid = blockIdx.x;
    const int t = threadIdx.x;

    if (bid < 768) {
        const int b = (bid < 384) ? bid : bid - 384;
        const int swz = (b & 7) * 48 + (b >> 3);
        if (bid < 384)
            gemm_body<2>(actA, Wq, bq_, Cq, 768, swz & 63, swz >> 6, nullptr, nullptr, AsS, BsS);
        else
            gemm_body<2>(actB, Wf, bf_, Cf, 768, swz & 63, swz >> 6, nullptr, nullptr, AsS, BsS);
    } else if (bid < 3072) {
        float (*tile)[33] = reinterpret_cast<float (*)[33]>(AsS);  // 4224 B alias
        const int g = bid - 768;
        const int wi = g / 576;   // 0..3 -> slots 2..5
        const int gx = g - wi * 576;
        const float* W = (wi == 0) ? w2 : (wi == 1) ? w3 : (wi == 2) ? w4 : w5;
        wt_transpose_block(W, Wall + (size_t)(wi + 2) * 768 * 768, gx, t, tile);
    } else {
        const int i = (bid - 3072) * 256 + t;  // 2*256*192 = 98304
        const int pair = i / (256 * 192);
        const int r = i - pair * (256 * 192);
        const int n = r / 192;
        const int k0 = (r - n * 192) * 4;
        const float* Woff = pair ? Woff_s : Woff_c;
        const float* Wa = pair ? Wa_s : Wa_c;
        _Float16* dst = pair ? Ws : Wc;
        _Float16* row = dst + (size_t)n * 768;
#pragma unroll
        for (int u = 0; u < 4; ++u) {
            const int k = k0 + u;
            float v = (n < 128) ? Woff[(size_t)k * 128 + n]
                    : (n < 192) ? Wa[(size_t)k * 64 + (n - 128)] : 0.f;
            row[k] = (_Float16)v;
        }
        if (k0 == 0) {
            const float* boff = pair ? boff_s : boff_c;
            const float* ba = pair ? ba_s : ba_c;
            float* bias = pair ? bias_s : bias_c;
            bias[n] = (n < 128) ? boff[n] : (n < 192) ? ba[n - 128] : 0.f;
        }
    }
}

// Single GEMM: N=768 (6 col tiles), 384 blocks, XCD-swizzled.
template <int MODE>
__global__ __launch_bounds__(256) void gemm_mfma(
    const _Float16* __restrict__ A, const _Float16* __restrict__ Wt,
    const float* __restrict__ bias, void* __restrict__ C,
    const _Float16* __restrict__ attn, const float* __restrict__ gamma)
{
    __shared__ _Float16 AsS[2 * 4096];
    __shared__ _Float16 BsS[2 * 4096];
    const int bid = blockIdx.x;
    const int swz = (bid & 7) * 48 + (bid >> 3);
    gemm_body<MODE>(A, Wt, bias, C, 768, swz & 63, swz >> 6, attn, gamma, AsS, BsS);
}

// Dual GEMM (both jobs MODE 2 / fp16 out): counts divisible by 8.
__global__ __launch_bounds__(256) void dual_gemm(
    const _Float16* __restrict__ A0, const _Float16* __restrict__ W0,
    const float* __restrict__ b0, _Float16* __restrict__ C0, int ldc0, int cnt0,
    const _Float16* __restrict__ A1, const _Float16* __restrict__ W1,
    const float* __restrict__ b1, _Float16* __restrict__ C1, int ldc1, int cnt1)
{
    __shared__ _Float16 AsS[2 * 4096];
    __shared__ _Float16 BsS[2 * 4096];
    int bid = blockIdx.x;
    if (bid < cnt0) {
        const int q = cnt0 >> 3;
        const int swz = (bid & 7) * q + (bid >> 3);
        gemm_body<2>(A0, W0, b0, C0, ldc0, swz & 63, swz >> 6, nullptr, nullptr, AsS, BsS);
    } else {
        bid -= cnt0;
        const int q = cnt1 >> 3;
        const int swz = (bid & 7) * q + (bid >> 3);
        gemm_body<2>(A1, W1, b1, C1, ldc1, swz & 63, swz >> 6, nullptr, nullptr, AsS, BsS);
    }
}

// ---------------------------------------------------------------------------
// LayerNorm, wave-per-row, fp16 in -> fp16 out. In-place safe.
// ---------------------------------------------------------------------------
__device__ __forceinline__ void ln_wave_body(
    const _Float16* __restrict__ X, _Float16* __restrict__ A,
    const float* __restrict__ g, const float* __restrict__ beta, int row)
{
    const int lane = threadIdx.x & 63;
    const _Float16* x = X + (size_t)row * D_MODEL;
    float v[12];
    float s = 0.f, s2 = 0.f;
#pragma unroll
    for (int j = 0; j < 12; ++j) {
        v[j] = (float)x[lane + 64 * j];
        s += v[j];
        s2 += v[j] * v[j];
    }
#pragma unroll
    for (int m = 1; m < 64; m <<= 1) {
        s += __shfl_xor(s, m);
        s2 += __shfl_xor(s2, m);
    }
    const float mean = s * (1.f / 768.f);
    const float var = s2 * (1.f / 768.f) - mean * mean;
    const float rstd = rsqrtf(var + 1e-6f);
    _Float16* arow = A + (size_t)row * D_MODEL;
#pragma unroll
    for (int j = 0; j < 12; ++j) {
        const int cc = lane + 64 * j;
        arow[cc] = (_Float16)((v[j] - mean) * rstd * g[cc] + beta[cc]);
    }
}

__global__ __launch_bounds__(256) void ln2_wave(
    const _Float16* __restrict__ X0, _Float16* __restrict__ A0,
    const float* __restrict__ g0, const float* __restrict__ b0,
    const _Float16* __restrict__ X1, _Float16* __restrict__ A1,
    const float* __restrict__ g1, const float* __restrict__ b1)
{
    const int r = blockIdx.x * 4 + (threadIdx.x >> 6);
    if (r < MTOT) ln_wave_body(X0, A0, g0, b0, r);
    else          ln_wave_body(X1, A1, g1, b1, r - MTOT);
}

__global__ __launch_bounds__(256) void ln_wave(
    const _Float16* __restrict__ X, _Float16* __restrict__ A,
    const float* __restrict__ g, const float* __restrict__ beta)
{
    const int r = blockIdx.x * 4 + (threadIdx.x >> 6);
    ln_wave_body(X, A, g, beta, r);
}

// ---------------------------------------------------------------------------
// Fused softmax/loc + bilinear sampling. 192-thread blocks, each covers 2 bq.
// offc is fp16 (M x 256): off at 0, aw at 128. XCD-chunk swizzle.
// ---------------------------------------------------------------------------
__global__ __launch_bounds__(192) void sample_fused(
    const _Float16* __restrict__ value, const _Float16* __restrict__ offc,
    _Float16* __restrict__ A)
{
    __shared__ float loc_s[32][8];
    __shared__ float aw_s[32][4];

    const int bid = blockIdx.x;                    // 4096 = 8 * 512
    const int swz = (bid & 7) * 512 + (bid >> 3);  // XCD-chunk swizzle
    const int bq_base = swz * 2;
    const int t = threadIdx.x;

    if (t < 32) {
        const int bq = bq_base + (t >> 4);
        const int h = t & 15;
        const int q = bq & (LQ - 1);
        const _Float16* orow = offc + (size_t)bq * 256 + h * 8;
        const _Float16* arow = offc + (size_t)bq * 256 + 128 + h * 4;
        float a0 = (float)arow[0], a1 = (float)arow[1], a2 = (float)arow[2], a3 = (float)arow[3];
        float mx = fmaxf(fmaxf(a0, a1), fmaxf(a2, a3));
        float e0 = expf(a0 - mx), e1 = expf(a1 - mx), e2 = expf(a2 - mx), e3 = expf(a3 - mx);
        float r = 1.f / (e0 + e1 + e2 + e3);
        const float refx = ((q & 63) + 0.5f) * (1.f / 64.f);
        const float refy = ((q >> 6) + 0.5f) * (1.f / 64.f);
#pragma unroll
        for (int p = 0; p < 4; ++p) {
            loc_s[t][p * 2 + 0] = refx + (float)orow[p * 2 + 0] * (1.f / 64.f);
            loc_s[t][p * 2 + 1] = refy + (float)orow[p * 2 + 1] * (1.f / 64.f);
        }
        aw_s[t][0] = e0 * r; aw_s[t][1] = e1 * r;
        aw_s[t][2] = e2 * r; aw_s[t][3] = e3 * r;
    }
    __syncthreads();

    const int lbqh = t / 6;
    const int c = t - lbqh * 6;
    const int d0 = c * 8;
    const int bq = bq_base + (lbqh >> 4);
    const int h = lbqh & 15;
    const int b = bq >> 12;

    const _Float16* vbase = value + (size_t)b * LQ * D_MODEL + h * DH + d0;

    float acc[8] = {};
#pragma unroll
    for (int p = 0; p < 4; ++p) {
        const float x = loc_s[lbqh][p * 2 + 0] * 64.f - 0.5f;
        const float y = loc_s[lbqh][p * 2 + 1] * 64.f - 0.5f;
        const float xf = floorf(x), yf = floorf(y);
        const float wx1 = x - xf, wy1 = y - yf;
        const float wx0 = 1.f - wx1, wy0 = 1.f - wy1;
        const int x0 = (int)xf, y0 = (int)yf;
        const int x1 = x0 + 1, y1 = y0 + 1;
        const float wp = aw_s[lbqh][p];
        const bool vx0 = (x0 >= 0) && (x0 < 64);
        const bool vx1 = (x1 >= 0) && (x1 < 64);
        const bool vy0 = (y0 >= 0) && (y0 < 64);
        const bool vy1 = (y1 >= 0) && (y1 < 64);
        const float cw[4] = {wp * wx0 * wy0, wp * wx1 * wy0, wp * wx0 * wy1, wp * wx1 * wy1};
        const bool cv[4] = {vx0 && vy0, vx1 && vy0, vx0 && vy1, vx1 && vy1};
        const int cxy[4][2] = {{x0, y0}, {x1, y0}, {x0, y1}, {x1, y1}};
#pragma unroll
        for (int k = 0; k < 4; ++k) {
            if (cv[k]) {
                const half8_t g = *(const half8_t*)(vbase + (size_t)(cxy[k][1] * 64 + cxy[k][0]) * D_MODEL);
#pragma unroll
                for (int u = 0; u < 8; ++u) acc[u] += cw[k] * (float)g[u];
            }
        }
    }

    _Float16* arow = A + (size_t)bq * D_MODEL + h * DH + d0;
    _Float16 o[8];
#pragma unroll
    for (int u = 0; u < 8; ++u) o[u] = (_Float16)acc[u];
    *(uint4*)arow = *(uint4*)o;
}

// ---------------------------------------------------------------------------
extern "C" void kernel_launch(void* const* d_in, const int* in_sizes, int n_in,
                              void* d_out, int out_size, void* d_ws, size_t ws_size,
                              hipStream_t stream)
{
    const float* query   = (const float*)d_in[0];
    const float* feat    = (const float*)d_in[1];
    const float* qn_W    = (const float*)d_in[4];
    const float* qn_b    = (const float*)d_in[5];
    const float* qn_g    = (const float*)d_in[6];
    const float* qn_beta = (const float*)d_in[7];
    const float* fn_W    = (const float*)d_in[8];
    const float* fn_b    = (const float*)d_in[9];
    const float* fn_g    = (const float*)d_in[10];
    const float* fn_beta = (const float*)d_in[11];
    const float* nm_g    = (const float*)d_in[12];
    const float* nm_beta = (const float*)d_in[13];
    const float* gamma1  = (const float*)d_in[14];
    const float* c_Wv    = (const float*)d_in[15];
    const float* c_bv    = (const float*)d_in[16];
    const float* c_Woff  = (const float*)d_in[17];
    const float* c_boff  = (const float*)d_in[18];
    const float* c_Wa    = (const float*)d_in[19];
    const float* c_ba    = (const float*)d_in[20];
    const float* c_Wo    = (const float*)d_in[21];
    const float* c_bo    = (const float*)d_in[22];
    const float* s_Wv    = (const float*)d_in[23];
    const float* s_bv    = (const float*)d_in[24];
    const float* s_Woff  = (const float*)d_in[25];
    const float* s_boff  = (const float*)d_in[26];
    const float* s_Wa    = (const float*)d_in[27];
    const float* s_ba    = (const float*)d_in[28];
    const float* s_Wo    = (const float*)d_in[29];
    const float* s_bo    = (const float*)d_in[30];

    const size_t SZ = (size_t)MTOT * D_MODEL;  // 6291456 elements
    _Float16* hA    = (_Float16*)d_ws;         // query16 -> attn16
    _Float16* hB    = hA + SZ;                 // feat16 -> samp16
    _Float16* hQ    = hB + SZ;                 // qn16 -> attn1n16
    _Float16* hF    = hQ + SZ;                 // fn16
    _Float16* val16 = hF + SZ;                 // value fp16
    _Float16* offc  = val16 + SZ;              // M x 256 fp16
    float* bias_c = (float*)(offc + (size_t)MTOT * 256);
    float* bias_s = bias_c + 256;
    _Float16* W6 = (_Float16*)(bias_s + 256);  // 6 x 768 x 768 fp16
    _Float16* W_qn  = W6 + (size_t)0 * 768 * 768;
    _Float16* W_fn  = W6 + (size_t)1 * 768 * 768;
    _Float16* W_cWv = W6 + (size_t)2 * 768 * 768;
    _Float16* W_cWo = W6 + (size_t)3 * 768 * 768;
    _Float16* W_sWv = W6 + (size_t)4 * 768 * 768;
    _Float16* W_sWo = W6 + (size_t)5 * 768 * 768;
    _Float16* Woffa_c = W6 + (size_t)6 * 768 * 768;  // 256 x 768
    _Float16* Woffa_s = Woffa_c + (size_t)256 * 768;

    float* out = (float*)d_out;
    const dim3 blk(256);

    // 1) acts -> fp16 + qn/fn weight transpose (G1's inputs only)
    convert_pre<<<13440, blk, 0, stream>>>(query, hA, feat, hB, qn_W, fn_W, W6);

    // 2) G1 mega: qn/fn GEMM (fp16-A, proven body) + remaining conversions
    //    riding on idle CUs; LDS aliased so footprint stays 32 KB.
    g1_mega<<<3456, blk, 0, stream>>>(
        hA, W_qn, qn_b, hQ,
        hB, W_fn, fn_b, hF,
        c_Wv, c_Wo, s_Wv, s_Wo, W6,
        c_Woff, c_Wa, c_boff, c_ba, s_Woff, s_Wa, s_boff, s_ba,
        Woffa_c, Woffa_s, bias_c, bias_s);

    // ---- cross attention ----
    ln2_wave<<<2 * MTOT / 4, blk, 0, stream>>>(hQ, hQ, qn_g, qn_beta,
                                               hF, hF, fn_g, fn_beta);
    dual_gemm<<<512, blk, 0, stream>>>(hF, W_cWv, c_bv, val16, 768, 384,
                                       hQ, Woffa_c, bias_c, offc, 256, 128);
    sample_fused<<<4096, dim3(192), 0, stream>>>(val16, offc, hB);
    gemm_mfma<2><<<384, blk, 0, stream>>>(hB, W_cWo, c_bo, hA, nullptr, nullptr);  // attn16

    // ---- self attention ----
    ln_wave<<<MTOT / 4, blk, 0, stream>>>(hA, hQ, nm_g, nm_beta);  // attn1 -> hQ
    dual_gemm<<<512, blk, 0, stream>>>(hQ, W_sWv, s_bv, val16, 768, 384,
                                       hQ, Woffa_s, bias_s, offc, 256, 128);
    sample_fused<<<4096, dim3(192), 0, stream>>>(val16, offc, hB);
    // final: out = gamma1 * (attn16 + samp@s_Wo + s_bo)
    gemm_mfma<1><<<384, blk, 0, stream>>>(hB, W_sWo, s_bo, out, hA, gamma1);
}